// Round 10
// baseline (734.160 us; speedup 1.0000x reference)
//
#include <hip/hip_runtime.h>
#include <hip/hip_bf16.h>
#include <stdint.h>

// SlotAttention MI355X. Round 10: PV moved to MFMA via one-time x-transpose.
//   - transpose_x: xT[b][d][l] (one-time, stage 1)
//   - fused_attn: dots + softmax + P(bf16) store + attn_sum (PV removed)
//   - pv_gemm: updraw = (P @ x) / attn_sum  as batched MFMA GEMM (M=16,K=2048)
//   - updates_finalize + part buffer removed.
// B=32 L=2048 D=1024 N=16 ITERS=4 H=2048.

typedef __bf16 bf16;
typedef __bf16 bf16x4 __attribute__((ext_vector_type(4)));
typedef __bf16 bf16x8 __attribute__((ext_vector_type(8)));
typedef float  f32x4  __attribute__((ext_vector_type(4)));

#define MFMA16(a,b,c) __builtin_amdgcn_mfma_f32_16x16x32_bf16((a),(b),(c),0,0,0)

__device__ __forceinline__ void gload16(const void* g, void* l) {
  __builtin_amdgcn_global_load_lds((__attribute__((address_space(1))) const void*)g,
                                   (__attribute__((address_space(3))) void*)l, 16, 0, 0);
}

// ---- shared 64x64 GEMM body: C[64,64] tile of A[M,K]@B[N,K]^T, 3-slot ring (r9, frozen) ----
template<int OUT_F32>
__device__ __forceinline__ void g64(const bf16* __restrict__ A, const bf16* __restrict__ B,
                                    void* __restrict__ C, int N, int K,
                                    int brow, int bcol, bf16* As, bf16* Bs)
{
  const int tid = threadIdx.x, wave = tid >> 6, lane = tid & 63;
  const int wm = wave >> 1, wn = wave & 1;
  const int r8 = lane >> 3, c8 = (lane & 7) * 8;
  const int cl = lane & 15, rh = lane >> 4;
  f32x4 acc[2][2] = {};

  const bf16* pa0 = A + (size_t)(brow + wave * 16 + r8) * K + c8;
  const bf16* pa1 = A + (size_t)(brow + wave * 16 + 8 + r8) * K + c8;
  const bf16* pb0 = B + (size_t)(bcol + wave * 16 + r8) * K + c8;
  const bf16* pb1 = B + (size_t)(bcol + wave * 16 + 8 + r8) * K + c8;

  auto ST = [&](int T) {
    const int k0 = T * 64, s = T % 3;
    gload16(pa0 + k0, As + s * 4096 + (wave * 16) * 64);
    gload16(pa1 + k0, As + s * 4096 + (wave * 16 + 8) * 64);
    gload16(pb0 + k0, Bs + s * 4096 + (wave * 16) * 64);
    gload16(pb1 + k0, Bs + s * 4096 + (wave * 16 + 8) * 64);
  };

  const int nt = K >> 6;
  ST(0);
  ST(1);
#pragma unroll 3
  for (int t = 0; t < nt; ++t) {
    __builtin_amdgcn_s_barrier();
    if (t + 2 < nt) {
      ST(t + 2);
      asm volatile("s_waitcnt vmcnt(8)" ::: "memory");
    } else if (t + 1 < nt) {
      asm volatile("s_waitcnt vmcnt(4)" ::: "memory");
    } else {
      asm volatile("s_waitcnt vmcnt(0)" ::: "memory");
    }
    __builtin_amdgcn_sched_barrier(0);
    __builtin_amdgcn_s_barrier();
    const int s = t % 3;
#pragma unroll
    for (int kk = 0; kk < 2; ++kk) {
      bf16x8 af[2], bfv[2];
#pragma unroll
      for (int m = 0; m < 2; ++m)
        af[m] = *(const bf16x8*)(As + s * 4096 + (wm * 32 + m * 16 + cl) * 64 + kk * 32 + rh * 8);
#pragma unroll
      for (int n = 0; n < 2; ++n)
        bfv[n] = *(const bf16x8*)(Bs + s * 4096 + (wn * 32 + n * 16 + cl) * 64 + kk * 32 + rh * 8);
#pragma unroll
      for (int m = 0; m < 2; ++m)
#pragma unroll
        for (int n = 0; n < 2; ++n)
          acc[m][n] = MFMA16(af[m], bfv[n], acc[m][n]);
    }
  }

#pragma unroll
  for (int m = 0; m < 2; ++m)
#pragma unroll
    for (int n = 0; n < 2; ++n) {
      int row0 = brow + wm * 32 + m * 16 + rh * 4;
      int col  = bcol + wn * 32 + n * 16 + cl;
#pragma unroll
      for (int r = 0; r < 4; ++r) {
        if (OUT_F32) ((float*)C)[(size_t)(row0 + r) * N + col] = acc[m][n][r];
        else         ((bf16*)C)[(size_t)(row0 + r) * N + col] = (bf16)acc[m][n][r];
      }
    }
}

// ---- z-selected 64x64 GEMM; zbuf: block(0,0,0) zeroes 512 floats ----
template<int OUT_F32>
__global__ __launch_bounds__(256, 3)
void gemm_bt64(const bf16* __restrict__ A0, const bf16* __restrict__ B0, void* __restrict__ C0,
               const bf16* __restrict__ A1, const bf16* __restrict__ B1, void* __restrict__ C1,
               int N, int K0, int K1, float* zbuf)
{
  __shared__ __align__(16) bf16 As[3 * 4096];
  __shared__ __align__(16) bf16 Bs[3 * 4096];
  if (zbuf != nullptr && blockIdx.x == 0 && blockIdx.y == 0 && blockIdx.z == 0) {
    zbuf[threadIdx.x] = 0.f;
    zbuf[threadIdx.x + 256] = 0.f;
  }
  const bf16* A = blockIdx.z ? A1 : A0;
  const bf16* B = blockIdx.z ? B1 : B0;
  void* C = blockIdx.z ? C1 : C0;
  const int K = blockIdx.z ? K1 : K0;
  g64<OUT_F32>(A, B, C, N, K, blockIdx.y * 64, blockIdx.x * 64, As, Bs);
}

// ---- one-time precompute GEMMs, single launch (2816 blocks) ----
__global__ __launch_bounds__(256, 3)
void gemm_pre(const bf16* __restrict__ wkT, const bf16* __restrict__ wqT, bf16* __restrict__ qm_w,
              const bf16* __restrict__ w12, const bf16* __restrict__ wvT, bf16* __restrict__ w12v,
              const bf16* __restrict__ wih, const bf16* __restrict__ w3T, bf16* __restrict__ wih3)
{
  __shared__ __align__(16) bf16 As[3 * 4096];
  __shared__ __align__(16) bf16 Bs[3 * 4096];
  const int id = blockIdx.x;
  if (id < 256)       g64<0>(wkT, wqT, qm_w, 1024, 1024, (id >> 4) * 64, (id & 15) * 64, As, Bs);
  else if (id < 1280) { int t = id - 256;  g64<0>(w12, wvT, w12v, 1024, 1024, (t >> 4) * 64, (t & 15) * 64, As, Bs); }
  else                { int t = id - 1280; g64<0>(wih, w3T, wih3, 2048, 1024, (t >> 5) * 64, (t & 31) * 64, As, Bs); }
}

// ---------------- pipelined SwiGLU GEMM (r8, frozen) ----------------
__global__ __launch_bounds__(256, 3)
void gemm_swiglu(const bf16* __restrict__ A, const bf16* __restrict__ B12, bf16* __restrict__ G)
{
  __shared__ __align__(16) bf16 As[2][64 * 64];
  __shared__ __align__(16) bf16 B1s[2][64 * 64];
  __shared__ __align__(16) bf16 B2s[2][64 * 64];
  const int tid = threadIdx.x, wave = tid >> 6, lane = tid & 63;
  const int wm = wave >> 1, wn = wave & 1;
  const int brow = blockIdx.y * 64, bcol = blockIdx.x * 64;
  const int r8 = lane >> 3, c8 = (lane & 7) * 8;
  const int cl = lane & 15, rh = lane >> 4;
  f32x4 acc1[2][2] = {}, acc2[2][2] = {};

  const bf16* pa0 = A   + (size_t)(brow + wave * 16 + r8) * 1024 + c8;
  const bf16* pa1 = A   + (size_t)(brow + wave * 16 + 8 + r8) * 1024 + c8;
  const bf16* p10 = B12 + (size_t)(bcol + wave * 16 + r8) * 1024 + c8;
  const bf16* p11 = B12 + (size_t)(bcol + wave * 16 + 8 + r8) * 1024 + c8;
  const bf16* p20 = B12 + (size_t)(2048 + bcol + wave * 16 + r8) * 1024 + c8;
  const bf16* p21 = B12 + (size_t)(2048 + bcol + wave * 16 + 8 + r8) * 1024 + c8;

#define STSW(T) {                                                   \
    int k0_ = (T) * 64, s_ = (T) & 1;                               \
    gload16(pa0 + k0_, &As[s_][(wave * 16) * 64]);                  \
    gload16(pa1 + k0_, &As[s_][(wave * 16 + 8) * 64]);              \
    gload16(p10 + k0_, &B1s[s_][(wave * 16) * 64]);                 \
    gload16(p11 + k0_, &B1s[s_][(wave * 16 + 8) * 64]);             \
    gload16(p20 + k0_, &B2s[s_][(wave * 16) * 64]);                 \
    gload16(p21 + k0_, &B2s[s_][(wave * 16 + 8) * 64]);             \
  }

  STSW(0)
  for (int t = 0; t < 16; ++t) {
    if (t < 15) {
      STSW(t + 1)
      asm volatile("s_waitcnt vmcnt(6)" ::: "memory");
    } else {
      asm volatile("s_waitcnt vmcnt(0)" ::: "memory");
    }
    __builtin_amdgcn_sched_barrier(0);
    __builtin_amdgcn_s_barrier();
    __builtin_amdgcn_sched_barrier(0);
    const int s = t & 1;
#pragma unroll
    for (int kk = 0; kk < 2; ++kk) {
      bf16x8 af[2], b1v[2], b2v[2];
#pragma unroll
      for (int m = 0; m < 2; ++m)
        af[m] = *(const bf16x8*)&As[s][(wm * 32 + m * 16 + cl) * 64 + kk * 32 + rh * 8];
#pragma unroll
      for (int n = 0; n < 2; ++n) {
        b1v[n] = *(const bf16x8*)&B1s[s][(wn * 32 + n * 16 + cl) * 64 + kk * 32 + rh * 8];
        b2v[n] = *(const bf16x8*)&B2s[s][(wn * 32 + n * 16 + cl) * 64 + kk * 32 + rh * 8];
      }
#pragma unroll
      for (int m = 0; m < 2; ++m)
#pragma unroll
        for (int n = 0; n < 2; ++n) {
          acc1[m][n] = MFMA16(af[m], b1v[n], acc1[m][n]);
          acc2[m][n] = MFMA16(af[m], b2v[n], acc2[m][n]);
        }
    }
    __builtin_amdgcn_sched_barrier(0);
    __builtin_amdgcn_s_barrier();
    __builtin_amdgcn_sched_barrier(0);
  }
#undef STSW

#pragma unroll
  for (int m = 0; m < 2; ++m)
#pragma unroll
    for (int n = 0; n < 2; ++n) {
      int row0 = brow + wm * 32 + m * 16 + rh * 4;
      int col  = bcol + wn * 32 + n * 16 + cl;
#pragma unroll
      for (int r = 0; r < 4; ++r) {
        float h1 = acc1[m][n][r], h2 = acc2[m][n][r];
        G[(size_t)(row0 + r) * 2048 + col] = (bf16)(h1 / (1.f + __expf(-h1)) * h2);
      }
    }
}

// ---------------- attention: dots (MFMA) + slot-softmax + P store ----------------
// qm [B*16,1024]; x = inputs [B,2048,1024]; P out [B*16,2048] bf16; attn_sum [B*16] f32.
__global__ __launch_bounds__(256, 2)
void fused_attn(const bf16* __restrict__ qm, const bf16* __restrict__ x,
                bf16* __restrict__ P, float* __restrict__ attn_sum)
{
  extern __shared__ __align__(16) char smem[];
  char* ss  = smem;                       // 32768: qm rows, XOR-swizzled
  char* ksl = smem + 32768;               // 2 * 16384: x slices

  const int lc = blockIdx.x, b = blockIdx.y;
  const int tid = threadIdx.x, wave = tid >> 6, lane = tid & 63;
  const int cl = lane & 15, rh = lane >> 4;

  const bf16* sb = qm + (size_t)b * 16 * 1024;
  {
    const int c16 = tid & 127, row2 = tid >> 7;
#pragma unroll
    for (int i = 0; i < 8; ++i) {
      int row = i * 2 + row2;
      int colb = (c16 * 16) ^ ((row & 7) << 4);
      gload16(sb + row * 1024 + colb / 2, ss + i * 4096 + wave * 1024);
    }
  }

  const bf16* kb = x + ((size_t)b * 2048 + lc * 128) * 1024;
  const int ksw  = ((lane & 7) ^ ((lane >> 3) & 7)) * 8;
  const int krow = wave * 8 + (lane >> 3);

#define STAGE_KS(KT) {                                                            \
    char* d_ = ksl + ((KT) & 1) * 16384;                                          \
    _Pragma("unroll")                                                             \
    for (int i = 0; i < 4; ++i)                                                   \
      gload16(kb + (size_t)(i * 32 + krow) * 1024 + (KT) * 64 + ksw,              \
              d_ + (i * 32 + wave * 8) * 128);                                    \
  }

  f32x4 acc[2] = {};
  STAGE_KS(0)
  for (int kt = 0; kt < 16; ++kt) {
    if (kt < 15) { STAGE_KS(kt + 1) }
    __builtin_amdgcn_sched_barrier(0);
    if (kt < 15) asm volatile("s_waitcnt vmcnt(4)" ::: "memory");
    else         asm volatile("s_waitcnt vmcnt(0)" ::: "memory");
    __builtin_amdgcn_sched_barrier(0);
    __builtin_amdgcn_s_barrier();
    const char* sbuf = ksl + (kt & 1) * 16384;
#pragma unroll
    for (int kk = 0; kk < 2; ++kk) {
      bf16x8 af = *(const bf16x8*)(ss + cl * 2048 +
                    ((kt * 128 + kk * 64 + rh * 16) ^ ((cl & 7) << 4)));
#pragma unroll
      for (int n = 0; n < 2; ++n) {
        int row = wave * 32 + n * 16 + cl;
        bf16x8 bfv = *(const bf16x8*)(sbuf + row * 128 +
                      ((kk * 64 + rh * 16) ^ ((row & 7) << 4)));
        acc[n] = MFMA16(af, bfv, acc[n]);
      }
    }
    __builtin_amdgcn_s_barrier();
    __builtin_amdgcn_sched_barrier(0);
  }
#undef STAGE_KS

  // softmax over 16 slots per column l; store P bf16, accumulate row sums
  const float scale = 0.03125f;   // 1024^-0.5
  float rs[4] = {0.f, 0.f, 0.f, 0.f};
#pragma unroll
  for (int n = 0; n < 2; ++n) {
    float xv[4];
#pragma unroll
    for (int r = 0; r < 4; ++r) xv[r] = acc[n][r] * scale;
    float mx = fmaxf(fmaxf(xv[0], xv[1]), fmaxf(xv[2], xv[3]));
    mx = fmaxf(mx, __shfl_xor(mx, 16));
    mx = fmaxf(mx, __shfl_xor(mx, 32));
    float e[4], sm = 0.f;
#pragma unroll
    for (int r = 0; r < 4; ++r) { e[r] = __expf(xv[r] - mx); sm += e[r]; }
    sm += __shfl_xor(sm, 16);
    sm += __shfl_xor(sm, 32);
    float inv = 1.f / sm;
    int l = lc * 128 + wave * 32 + n * 16 + cl;
#pragma unroll
    for (int r = 0; r < 4; ++r) {
      float av = e[r] * inv;
      rs[r] += av;
      P[((size_t)b * 16 + rh * 4 + r) * 2048 + l] = (bf16)av;
    }
  }
#pragma unroll
  for (int off = 1; off < 16; off <<= 1) {
#pragma unroll
    for (int r = 0; r < 4; ++r) rs[r] += __shfl_xor(rs[r], off);
  }
  if (cl == 0) {
#pragma unroll
    for (int r = 0; r < 4; ++r) atomicAdd(&attn_sum[b * 16 + rh * 4 + r], rs[r]);
  }
}

// ---------------- PV as batched MFMA GEMM + normalize epilogue ----------------
// updraw[b*16+slot][d] = (sum_l P[b,slot,l] * xT[b,d,l]) / (attn_sum+eps)
// grid (16 d-tiles, 32 b). M=16, N=64/block, K=2048. 3-slot LDS ring.
__global__ __launch_bounds__(256, 4)
void pv_gemm(const bf16* __restrict__ P, const bf16* __restrict__ xT,
             const float* __restrict__ attn_sum, bf16* __restrict__ updraw)
{
  __shared__ __align__(16) bf16 Ap[3 * 1024];   // 3 x [16][64]
  __shared__ __align__(16) bf16 Bp[3 * 4096];   // 3 x [64][64]
  const int dt = blockIdx.x, b = blockIdx.y;
  const int tid = threadIdx.x, wave = tid >> 6;
  const int lane = tid & 63, cl = lane & 15, rh = lane >> 4;

  const bf16* Pb = P  + (size_t)b * 16 * 2048;
  const bf16* Xb = xT + ((size_t)b * 1024 + dt * 64) * 2048;
  const int rrow = tid >> 3, rcol = (tid & 7) * 8;

  auto ST = [&](int T) {
    const int k0 = T * 64, s = T % 3;
    gload16(Xb + (size_t)rrow * 2048 + k0 + rcol,        Bp + s * 4096 + wave * 512);
    gload16(Xb + (size_t)(32 + rrow) * 2048 + k0 + rcol, Bp + s * 4096 + 2048 + wave * 512);
    if (tid < 128)   // waves 0,1 stage A (16 rows x 64)
      gload16(Pb + (size_t)rrow * 2048 + k0 + rcol, Ap + s * 1024 + wave * 512);
  };

  f32x4 acc = {};
  ST(0);
  ST(1);
#pragma unroll 3
  for (int t = 0; t < 32; ++t) {
    __builtin_amdgcn_s_barrier();
    if (t + 2 < 32) {
      ST(t + 2);
      asm volatile("s_waitcnt vmcnt(4)" ::: "memory");   // valid for both wave classes (3/2 loads per stage)
    } else if (t + 1 < 32) {
      asm volatile("s_waitcnt vmcnt(2)" ::: "memory");
    } else {
      asm volatile("s_waitcnt vmcnt(0)" ::: "memory");
    }
    __builtin_amdgcn_sched_barrier(0);
    __builtin_amdgcn_s_barrier();
    const int s = t % 3;
#pragma unroll
    for (int kk = 0; kk < 2; ++kk) {
      bf16x8 af  = *(const bf16x8*)(Ap + s * 1024 + cl * 64 + kk * 32 + rh * 8);
      bf16x8 bfv = *(const bf16x8*)(Bp + s * 4096 + (wave * 16 + cl) * 64 + kk * 32 + rh * 8);
      acc = MFMA16(af, bfv, acc);
    }
  }

  const int dcol = dt * 64 + wave * 16 + cl;
#pragma unroll
  for (int j = 0; j < 4; ++j) {
    int slot = rh * 4 + j;
    float inv = 1.f / (attn_sum[b * 16 + slot] + 1e-8f);
    updraw[((size_t)b * 16 + slot) * 1024 + dcol] = (bf16)(acc[j] * inv);
  }
}

// ---------------- one-time x transpose: [B,2048,1024] -> [B,1024,2048] bf16 ----------------
__global__ __launch_bounds__(256)
void transpose_x(const bf16* __restrict__ in, bf16* __restrict__ out)
{
  __shared__ bf16 tile[64][72];
  const int l0 = blockIdx.x * 64, d0 = blockIdx.y * 64, b = blockIdx.z;
  const int t = threadIdx.x;
  const int r = t >> 3, c = (t & 7) * 8;
#pragma unroll
  for (int i = 0; i < 2; ++i) {
    int row = i * 32 + r;
    bf16x8 v = *(const bf16x8*)(in + ((size_t)(b * 2048 + l0 + row)) * 1024 + d0 + c);
    *(bf16x8*)&tile[row][c] = v;
  }
  __syncthreads();
#pragma unroll
  for (int i = 0; i < 2; ++i) {
    int drow = i * 32 + r;
    bf16x8 o;
#pragma unroll
    for (int j = 0; j < 8; ++j) o[j] = tile[c + j][drow];
    *(bf16x8*)(out + ((size_t)b * 1024 + d0 + drow) * 2048 + l0 + c) = o;
  }
}

// ---------------- GRU pointwise + fused rmsnorm ----------------
__global__ __launch_bounds__(256)
void gru_pw_fused(const float* __restrict__ gi, const float* __restrict__ gh,
                  const float* __restrict__ bih, const float* __restrict__ bhh,
                  const float* __restrict__ g_sl,
                  float* __restrict__ slots, bf16* __restrict__ slots_bf,
                  bf16* __restrict__ s_bf, float* __restrict__ outp)
{
  const int m = blockIdx.x, tid = threadIdx.x;
  const int d0 = tid * 4;
  const size_t base = (size_t)m * 3072 + d0;
  f32x4 gir = *(const f32x4*)(gi + base),        ghr = *(const f32x4*)(gh + base);
  f32x4 giz = *(const f32x4*)(gi + base + 1024), ghz = *(const f32x4*)(gh + base + 1024);
  f32x4 gin = *(const f32x4*)(gi + base + 2048), ghn = *(const f32x4*)(gh + base + 2048);
  f32x4 br  = *(const f32x4*)(bih + d0),        bhr = *(const f32x4*)(bhh + d0);
  f32x4 bz  = *(const f32x4*)(bih + 1024 + d0), bhz = *(const f32x4*)(bhh + 1024 + d0);
  f32x4 bn  = *(const f32x4*)(bih + 2048 + d0), bhn = *(const f32x4*)(bhh + 2048 + d0);
  f32x4 h   = *(const f32x4*)(slots + (size_t)m * 1024 + d0);
  float o[4]; float ssum = 0.f;
#pragma unroll
  for (int j = 0; j < 4; ++j) {
    float r  = gir[j] + br[j] + ghr[j] + bhr[j];
    float z  = giz[j] + bz[j] + ghz[j] + bhz[j];
    float nn = gin[j] + bn[j];
    float hn = ghn[j] + bhn[j];
    r = 1.f / (1.f + expf(-r));
    z = 1.f / (1.f + expf(-z));
    nn = tanhf(nn + r * hn);
    o[j] = (1.f - z) * nn + z * h[j];
    ssum += o[j] * o[j];
  }
#pragma unroll
  for (int off = 32; off; off >>= 1) ssum += __shfl_xor(ssum, off);
  __shared__ float red[4];
  if ((tid & 63) == 0) red[tid >> 6] = ssum;
  __syncthreads();
  float tot = red[0] + red[1] + red[2] + red[3];
  float rsc = rsqrtf(tot * (1.f / 1024.f) + 1e-6f);
  f32x4 gv = *(const f32x4*)(g_sl + d0);
  f32x4 of; bf16x4 ob, sb;
#pragma unroll
  for (int j = 0; j < 4; ++j) { of[j] = o[j]; ob[j] = (bf16)o[j]; sb[j] = (bf16)(o[j] * rsc * gv[j]); }
  *(f32x4*)(slots + (size_t)m * 1024 + d0) = of;
  *(f32x4*)(outp  + (size_t)m * 1024 + d0) = of;
  *(bf16x4*)(slots_bf + (size_t)m * 1024 + d0) = ob;
  *(bf16x4*)(s_bf     + (size_t)m * 1024 + d0) = sb;
}

__global__ __launch_bounds__(256)
void init_slots_fused(const float* __restrict__ noise, const float* __restrict__ mu,
                      const float* __restrict__ sigma, const float* __restrict__ g_sl,
                      float* __restrict__ slots, bf16* __restrict__ slots_bf,
                      bf16* __restrict__ s_bf)
{
  const int m = blockIdx.x, tid = threadIdx.x;
  const int d0 = tid * 4;
  f32x4 nz = *(const f32x4*)(noise + (size_t)m * 1024 + d0);
  f32x4 mv = *(const f32x4*)(mu + d0);
  f32x4 sg = *(const f32x4*)(sigma + d0);
  float o[4]; float ssum = 0.f;
#pragma unroll
  for (int j = 0; j < 4; ++j) { o[j] = mv[j] + sg[j] * nz[j]; ssum += o[j] * o[j]; }
#pragma unroll
  for (int off = 32; off; off >>= 1) ssum += __shfl_xor(ssum, off);
  __shared__ float red[4];
  if ((tid & 63) == 0) red[tid >> 6] = ssum;
  __syncthreads();
  float tot = red[0] + red[1] + red[2] + red[3];
  float rsc = rsqrtf(tot * (1.f / 1024.f) + 1e-6f);
  f32x4 gv = *(const f32x4*)(g_sl + d0);
  f32x4 of; bf16x4 ob, sb;
#pragma unroll
  for (int j = 0; j < 4; ++j) { of[j] = o[j]; ob[j] = (bf16)o[j]; sb[j] = (bf16)(o[j] * rsc * gv[j]); }
  *(f32x4*)(slots + (size_t)m * 1024 + d0) = of;
  *(bf16x4*)(slots_bf + (size_t)m * 1024 + d0) = ob;
  *(bf16x4*)(s_bf     + (size_t)m * 1024 + d0) = sb;
}

__global__ __launch_bounds__(256)
void rmsnorm_cast(const float* __restrict__ x, const float* __restrict__ g, bf16* __restrict__ y)
{
  const int row = blockIdx.x, tid = threadIdx.x;
  float4 xv = ((const float4*)(x + (size_t)row * 1024))[tid];
  float ss = xv.x * xv.x + xv.y * xv.y + xv.z * xv.z + xv.w * xv.w;
#pragma unroll
  for (int off = 32; off; off >>= 1) ss += __shfl_xor(ss, off);
  __shared__ float red[4];
  if ((tid & 63) == 0) red[tid >> 6] = ss;
  __syncthreads();
  float tot = red[0] + red[1] + red[2] + red[3];
  float rs = rsqrtf(tot * (1.f / 1024.f) + 1e-6f);
  float4 gv = ((const float4*)g)[tid];
  bf16x4 o;
  o[0] = (bf16)(xv.x * rs * gv.x); o[1] = (bf16)(xv.y * rs * gv.y);
  o[2] = (bf16)(xv.z * rs * gv.z); o[3] = (bf16)(xv.w * rs * gv.w);
  *(bf16x4*)(y + (size_t)row * 1024 + tid * 4) = o;
}

// ---- batched transposes: z=0..2 Wq/Wk/Wv (1024^2); z=3 w3 [1024,2048] ----
__global__ __launch_bounds__(256)
void transpose_all(const float* __restrict__ Wq, const float* __restrict__ Wk,
                   const float* __restrict__ Wv, const float* __restrict__ w3,
                   bf16* __restrict__ wqT, bf16* __restrict__ wkT,
                   bf16* __restrict__ wvT, bf16* __restrict__ w3T)
{
  __shared__ float tile[32][33];
  const int z = blockIdx.z;
  const float* in; bf16* out; int R, C;
  if      (z == 0) { in = Wq; out = wqT; R = 1024; C = 1024; }
  else if (z == 1) { in = Wk; out = wkT; R = 1024; C = 1024; }
  else if (z == 2) { in = Wv; out = wvT; R = 1024; C = 1024; }
  else             { in = w3; out = w3T; R = 1024; C = 2048; }
  const int bx = blockIdx.x * 32, by = blockIdx.y * 32;
  if (bx >= C) return;
  const int tx = threadIdx.x & 31, ty = threadIdx.x >> 5;
#pragma unroll
  for (int i = 0; i < 32; i += 8)
    tile[ty + i][tx] = in[(size_t)(by + ty + i) * C + bx + tx];
  __syncthreads();
#pragma unroll
  for (int i = 0; i < 32; i += 8)
    out[(size_t)(bx + ty + i) * R + by + tx] = (bf16)tile[tx][ty + i];
}

// ---- flat cast: w1,w2 -> w12_bf ; Wih -> wih_bf ; Whh -> whh_b ----
__global__ void cast_all(const float* __restrict__ w1, const float* __restrict__ w2,
                         const float* __restrict__ Wih, const float* __restrict__ Whh,
                         bf16* __restrict__ w12_bf, bf16* __restrict__ wih_bf,
                         bf16* __restrict__ whh_b)
{
  int i = (blockIdx.x * 256 + threadIdx.x) * 4;      // over 10485760
  const float* src; bf16* dst; int o;
  if      (i < 2097152)  { src = w1;  dst = w12_bf; o = i; }
  else if (i < 4194304)  { src = w2;  dst = w12_bf + 2097152; o = i - 2097152; }
  else if (i < 7340032)  { src = Wih; dst = wih_bf; o = i - 4194304; }
  else                   { src = Whh; dst = whh_b;  o = i - 7340032; }
  float4 v = *(const float4*)(src + o);
  bf16x4 ov; ov[0] = (bf16)v.x; ov[1] = (bf16)v.y; ov[2] = (bf16)v.z; ov[3] = (bf16)v.w;
  *(bf16x4*)(dst + o) = ov;
}

// ---------------- host ----------------
extern "C" void kernel_launch(void* const* d_in, const int* in_sizes, int n_in,
                              void* d_out, int out_size, void* d_ws, size_t ws_size,
                              hipStream_t stream)
{
  const float* enc    = (const float*)d_in[0];
  const float* noise  = (const float*)d_in[1];
  const float* mu     = (const float*)d_in[2];
  const float* sigma  = (const float*)d_in[3];
  const float* g_in   = (const float*)d_in[4];
  const float* g_sl   = (const float*)d_in[5];
  const float* Wq     = (const float*)d_in[6];
  const float* Wk     = (const float*)d_in[7];
  const float* Wv     = (const float*)d_in[8];
  const float* w1     = (const float*)d_in[9];
  const float* w2     = (const float*)d_in[10];
  const float* w3     = (const float*)d_in[11];
  const float* Wih    = (const float*)d_in[12];
  const float* Whh    = (const float*)d_in[13];
  const float* bih    = (const float*)d_in[14];
  const float* bhh    = (const float*)d_in[15];

  char* p = (char*)d_ws;
  auto alloc = [&](size_t bytes) { char* r = p; p += (bytes + 255) & ~(size_t)255; return (void*)r; };

  bf16* inputs  = (bf16*)alloc((size_t)32 * 2048 * 1024 * 2);  // 128MB, dots operand
  bf16* xT      = (bf16*)alloc((size_t)32 * 1024 * 2048 * 2);  // 128MB, PV operand
  bf16* qm_w    = (bf16*)alloc((size_t)1024 * 1024 * 2);
  bf16* wqT_b   = (bf16*)alloc((size_t)1024 * 1024 * 2);
  bf16* wkT_b   = (bf16*)alloc((size_t)1024 * 1024 * 2);
  bf16* wvT_b   = (bf16*)alloc((size_t)1024 * 1024 * 2);
  bf16* w3T_b   = (bf16*)alloc((size_t)2048 * 1024 * 2);
  bf16* w12_bf  = (bf16*)alloc((size_t)4096 * 1024 * 2);
  bf16* w12v    = (bf16*)alloc((size_t)4096 * 1024 * 2);
  bf16* wih_bf  = (bf16*)alloc((size_t)3072 * 1024 * 2);
  bf16* wih3_b  = (bf16*)alloc((size_t)3072 * 2048 * 2);
  bf16* whh_b   = (bf16*)alloc((size_t)3072 * 1024 * 2);
  float* slots  = (float*)alloc(512 * 1024 * 4);
  bf16* slots_bf= (bf16*)alloc(512 * 1024 * 2);
  bf16* s_bf    = (bf16*)alloc(512 * 1024 * 2);
  bf16* qm_bf   = (bf16*)alloc(512 * 1024 * 2);
  float* attn_sum = (float*)alloc(32 * 16 * 4);
  bf16* Pbuf    = (bf16*)alloc((size_t)32 * 16 * 2048 * 2);    // 2MB
  bf16* updraw  = (bf16*)alloc(512 * 1024 * 2);
  bf16* g_bf    = (bf16*)alloc((size_t)512 * 2048 * 2);
  float* gif    = (float*)alloc((size_t)512 * 3072 * 4);
  float* ghf    = (float*)alloc((size_t)512 * 3072 * 4);

  // ---- precompute: 3 launches ----
  transpose_all<<<dim3(64, 32, 4), 256, 0, stream>>>(Wq, Wk, Wv, w3, wqT_b, wkT_b, wvT_b, w3T_b);
  cast_all<<<10240, 256, 0, stream>>>(w1, w2, Wih, Whh, w12_bf, wih_bf, whh_b);
  gemm_pre<<<2816, 256, 0, stream>>>(wkT_b, wqT_b, qm_w, w12_bf, wvT_b, w12v, wih_bf, w3T_b, wih3_b);

  // ---- stage 1 ----
  rmsnorm_cast<<<65536, 256, 0, stream>>>(enc, g_in, inputs);
  transpose_x<<<dim3(32, 16, 32), 256, 0, stream>>>(inputs, xT);
  init_slots_fused<<<512, 256, 0, stream>>>(noise, mu, sigma, g_sl, slots, slots_bf, s_bf);

  hipFuncSetAttribute(reinterpret_cast<const void*>(fused_attn),
                      hipFuncAttributeMaxDynamicSharedMemorySize, 65536);

  // ---- iterations (6 launches each) ----
  for (int it = 0; it < 4; ++it) {
    gemm_bt64<0><<<dim3(16, 8, 1), 256, 0, stream>>>(s_bf, qm_w, qm_bf, s_bf, qm_w, qm_bf,
                                                     1024, 1024, 1024, attn_sum);
    fused_attn<<<dim3(16, 32), 256, 65536, stream>>>(qm_bf, inputs, Pbuf, attn_sum);
    pv_gemm<<<dim3(16, 32), 256, 0, stream>>>(Pbuf, xT, attn_sum, updraw);
    gemm_swiglu<<<dim3(32, 8), 256, 0, stream>>>(updraw, w12v, g_bf);
    gemm_bt64<1><<<dim3(48, 8, 2), 256, 0, stream>>>(g_bf, wih3_b, gif, slots_bf, whh_b, ghf,
                                                     3072, 2048, 1024, nullptr);
    float* outp = (it == 3) ? (float*)d_out : slots;
    gru_pw_fused<<<512, 256, 0, stream>>>(gif, ghf, bih, bhh, g_sl, slots, slots_bf, s_bf, outp);
  }
}

// Round 11
// 669.361 us; speedup vs baseline: 1.0968x; 1.0968x over previous
//
#include <hip/hip_runtime.h>
#include <hip/hip_bf16.h>
#include <stdint.h>

// SlotAttention MI355X. Round 11: r9 base (r10 pv_gemm reverted — xT stream-bound).
//   + PV inner loop as f32x2 slot-pairs (v_pk_fma_f32, 2x fp32 FMA rate)
//   + precompute GEMMs on 128^2 tiles (gemm_pre128, 704 blocks)
// B=32 L=2048 D=1024 N=16 ITERS=4 H=2048.

typedef __bf16 bf16;
typedef __bf16 bf16x4 __attribute__((ext_vector_type(4)));
typedef __bf16 bf16x8 __attribute__((ext_vector_type(8)));
typedef float  f32x2  __attribute__((ext_vector_type(2)));
typedef float  f32x4  __attribute__((ext_vector_type(4)));

#define MFMA16(a,b,c) __builtin_amdgcn_mfma_f32_16x16x32_bf16((a),(b),(c),0,0,0)

__device__ __forceinline__ void gload16(const void* g, void* l) {
  __builtin_amdgcn_global_load_lds((__attribute__((address_space(1))) const void*)g,
                                   (__attribute__((address_space(3))) void*)l, 16, 0, 0);
}

// ---- shared 64x64 GEMM body: C[64,64] tile of A[M,K]@B[N,K]^T, 3-slot ring (r9, frozen) ----
template<int OUT_F32>
__device__ __forceinline__ void g64(const bf16* __restrict__ A, const bf16* __restrict__ B,
                                    void* __restrict__ C, int N, int K,
                                    int brow, int bcol, bf16* As, bf16* Bs)
{
  const int tid = threadIdx.x, wave = tid >> 6, lane = tid & 63;
  const int wm = wave >> 1, wn = wave & 1;
  const int r8 = lane >> 3, c8 = (lane & 7) * 8;
  const int cl = lane & 15, rh = lane >> 4;
  f32x4 acc[2][2] = {};

  const bf16* pa0 = A + (size_t)(brow + wave * 16 + r8) * K + c8;
  const bf16* pa1 = A + (size_t)(brow + wave * 16 + 8 + r8) * K + c8;
  const bf16* pb0 = B + (size_t)(bcol + wave * 16 + r8) * K + c8;
  const bf16* pb1 = B + (size_t)(bcol + wave * 16 + 8 + r8) * K + c8;

  auto ST = [&](int T) {
    const int k0 = T * 64, s = T % 3;
    gload16(pa0 + k0, As + s * 4096 + (wave * 16) * 64);
    gload16(pa1 + k0, As + s * 4096 + (wave * 16 + 8) * 64);
    gload16(pb0 + k0, Bs + s * 4096 + (wave * 16) * 64);
    gload16(pb1 + k0, Bs + s * 4096 + (wave * 16 + 8) * 64);
  };

  const int nt = K >> 6;
  ST(0);
  ST(1);
#pragma unroll 3
  for (int t = 0; t < nt; ++t) {
    __builtin_amdgcn_s_barrier();
    if (t + 2 < nt) {
      ST(t + 2);
      asm volatile("s_waitcnt vmcnt(8)" ::: "memory");
    } else if (t + 1 < nt) {
      asm volatile("s_waitcnt vmcnt(4)" ::: "memory");
    } else {
      asm volatile("s_waitcnt vmcnt(0)" ::: "memory");
    }
    __builtin_amdgcn_sched_barrier(0);
    __builtin_amdgcn_s_barrier();
    const int s = t % 3;
#pragma unroll
    for (int kk = 0; kk < 2; ++kk) {
      bf16x8 af[2], bfv[2];
#pragma unroll
      for (int m = 0; m < 2; ++m)
        af[m] = *(const bf16x8*)(As + s * 4096 + (wm * 32 + m * 16 + cl) * 64 + kk * 32 + rh * 8);
#pragma unroll
      for (int n = 0; n < 2; ++n)
        bfv[n] = *(const bf16x8*)(Bs + s * 4096 + (wn * 32 + n * 16 + cl) * 64 + kk * 32 + rh * 8);
#pragma unroll
      for (int m = 0; m < 2; ++m)
#pragma unroll
        for (int n = 0; n < 2; ++n)
          acc[m][n] = MFMA16(af[m], bfv[n], acc[m][n]);
    }
  }

#pragma unroll
  for (int m = 0; m < 2; ++m)
#pragma unroll
    for (int n = 0; n < 2; ++n) {
      int row0 = brow + wm * 32 + m * 16 + rh * 4;
      int col  = bcol + wn * 32 + n * 16 + cl;
#pragma unroll
      for (int r = 0; r < 4; ++r) {
        if (OUT_F32) ((float*)C)[(size_t)(row0 + r) * N + col] = acc[m][n][r];
        else         ((bf16*)C)[(size_t)(row0 + r) * N + col] = (bf16)acc[m][n][r];
      }
    }
}

// ---- z-selected 64x64 GEMM; zbuf: block(0,0,0) zeroes 512 floats ----
template<int OUT_F32>
__global__ __launch_bounds__(256, 3)
void gemm_bt64(const bf16* __restrict__ A0, const bf16* __restrict__ B0, void* __restrict__ C0,
               const bf16* __restrict__ A1, const bf16* __restrict__ B1, void* __restrict__ C1,
               int N, int K0, int K1, float* zbuf)
{
  __shared__ __align__(16) bf16 As[3 * 4096];
  __shared__ __align__(16) bf16 Bs[3 * 4096];
  if (zbuf != nullptr && blockIdx.x == 0 && blockIdx.y == 0 && blockIdx.z == 0) {
    zbuf[threadIdx.x] = 0.f;
    zbuf[threadIdx.x + 256] = 0.f;
  }
  const bf16* A = blockIdx.z ? A1 : A0;
  const bf16* B = blockIdx.z ? B1 : B0;
  void* C = blockIdx.z ? C1 : C0;
  const int K = blockIdx.z ? K1 : K0;
  g64<OUT_F32>(A, B, C, N, K, blockIdx.y * 64, blockIdx.x * 64, As, Bs);
}

// ---- 128x128 GEMM body (r3-proven, 2-barrier): C tile of A[M,K]@B[N,K]^T, bf16 out ----
__device__ __forceinline__ void g128(const bf16* __restrict__ A, const bf16* __restrict__ B,
                                     bf16* __restrict__ C, int N, int K,
                                     int brow, int bcol, bf16* As, bf16* Bs)
{
  const int tid  = threadIdx.x;
  const int wave = tid >> 6, lane = tid & 63;
  const int wm = wave >> 1, wn = wave & 1;
  const int r_a = lane >> 3, c_a = (lane & 7) * 8;
  const int cl = lane & 15, rh = lane >> 4;

  f32x4 acc[4][4] = {};

  for (int k0 = 0; k0 < K; k0 += 64) {
    __syncthreads();
#pragma unroll
    for (int i = 0; i < 4; ++i) {
      gload16(A + (size_t)(brow + i * 32 + wave * 8 + r_a) * K + k0 + c_a, &As[(i * 32 + wave * 8) * 64]);
      gload16(B + (size_t)(bcol + i * 32 + wave * 8 + r_a) * K + k0 + c_a, &Bs[(i * 32 + wave * 8) * 64]);
    }
    __syncthreads();
#pragma unroll
    for (int kk = 0; kk < 2; ++kk) {
      bf16x8 af[4], bfv[4];
#pragma unroll
      for (int m = 0; m < 4; ++m)
        af[m] = *(const bf16x8*)&As[(wm * 64 + m * 16 + cl) * 64 + kk * 32 + rh * 8];
#pragma unroll
      for (int n = 0; n < 4; ++n)
        bfv[n] = *(const bf16x8*)&Bs[(wn * 64 + n * 16 + cl) * 64 + kk * 32 + rh * 8];
#pragma unroll
      for (int m = 0; m < 4; ++m)
#pragma unroll
        for (int n = 0; n < 4; ++n)
          acc[m][n] = MFMA16(af[m], bfv[n], acc[m][n]);
    }
  }
#pragma unroll
  for (int m = 0; m < 4; ++m)
#pragma unroll
    for (int n = 0; n < 4; ++n) {
      int row0 = brow + wm * 64 + m * 16 + rh * 4;
      int col  = bcol + wn * 64 + n * 16 + cl;
#pragma unroll
      for (int r = 0; r < 4; ++r)
        C[(size_t)(row0 + r) * N + col] = (bf16)acc[m][n][r];
    }
}

// ---- one-time precompute GEMMs on 128^2 tiles, single launch (704 blocks) ----
// id<64: qm_w[1024,1024]=wkT@wqT^T ; id<320: w12v[4096,1024]=w12@wvT^T ;
// else: wih3[3072,2048]=wih@w3T^T.  All K=1024.
__global__ __launch_bounds__(256, 2)
void gemm_pre128(const bf16* __restrict__ wkT, const bf16* __restrict__ wqT, bf16* __restrict__ qm_w,
                 const bf16* __restrict__ w12, const bf16* __restrict__ wvT, bf16* __restrict__ w12v,
                 const bf16* __restrict__ wih, const bf16* __restrict__ w3T, bf16* __restrict__ wih3)
{
  __shared__ __align__(16) bf16 As[128 * 64];
  __shared__ __align__(16) bf16 Bs[128 * 64];
  const int id = blockIdx.x;
  if (id < 64)        g128(wkT, wqT, qm_w, 1024, 1024, (id >> 3) * 128, (id & 7) * 128, As, Bs);
  else if (id < 320) { int t = id - 64;  g128(w12, wvT, w12v, 1024, 1024, (t >> 3) * 128, (t & 7) * 128, As, Bs); }
  else               { int t = id - 320; g128(wih, w3T, wih3, 2048, 1024, (t >> 4) * 128, (t & 15) * 128, As, Bs); }
}

// ---------------- pipelined SwiGLU GEMM (r8, frozen) ----------------
__global__ __launch_bounds__(256, 3)
void gemm_swiglu(const bf16* __restrict__ A, const bf16* __restrict__ B12, bf16* __restrict__ G)
{
  __shared__ __align__(16) bf16 As[2][64 * 64];
  __shared__ __align__(16) bf16 B1s[2][64 * 64];
  __shared__ __align__(16) bf16 B2s[2][64 * 64];
  const int tid = threadIdx.x, wave = tid >> 6, lane = tid & 63;
  const int wm = wave >> 1, wn = wave & 1;
  const int brow = blockIdx.y * 64, bcol = blockIdx.x * 64;
  const int r8 = lane >> 3, c8 = (lane & 7) * 8;
  const int cl = lane & 15, rh = lane >> 4;
  f32x4 acc1[2][2] = {}, acc2[2][2] = {};

  const bf16* pa0 = A   + (size_t)(brow + wave * 16 + r8) * 1024 + c8;
  const bf16* pa1 = A   + (size_t)(brow + wave * 16 + 8 + r8) * 1024 + c8;
  const bf16* p10 = B12 + (size_t)(bcol + wave * 16 + r8) * 1024 + c8;
  const bf16* p11 = B12 + (size_t)(bcol + wave * 16 + 8 + r8) * 1024 + c8;
  const bf16* p20 = B12 + (size_t)(2048 + bcol + wave * 16 + r8) * 1024 + c8;
  const bf16* p21 = B12 + (size_t)(2048 + bcol + wave * 16 + 8 + r8) * 1024 + c8;

#define STSW(T) {                                                   \
    int k0_ = (T) * 64, s_ = (T) & 1;                               \
    gload16(pa0 + k0_, &As[s_][(wave * 16) * 64]);                  \
    gload16(pa1 + k0_, &As[s_][(wave * 16 + 8) * 64]);              \
    gload16(p10 + k0_, &B1s[s_][(wave * 16) * 64]);                 \
    gload16(p11 + k0_, &B1s[s_][(wave * 16 + 8) * 64]);             \
    gload16(p20 + k0_, &B2s[s_][(wave * 16) * 64]);                 \
    gload16(p21 + k0_, &B2s[s_][(wave * 16 + 8) * 64]);             \
  }

  STSW(0)
  for (int t = 0; t < 16; ++t) {
    if (t < 15) {
      STSW(t + 1)
      asm volatile("s_waitcnt vmcnt(6)" ::: "memory");
    } else {
      asm volatile("s_waitcnt vmcnt(0)" ::: "memory");
    }
    __builtin_amdgcn_sched_barrier(0);
    __builtin_amdgcn_s_barrier();
    __builtin_amdgcn_sched_barrier(0);
    const int s = t & 1;
#pragma unroll
    for (int kk = 0; kk < 2; ++kk) {
      bf16x8 af[2], b1v[2], b2v[2];
#pragma unroll
      for (int m = 0; m < 2; ++m)
        af[m] = *(const bf16x8*)&As[s][(wm * 32 + m * 16 + cl) * 64 + kk * 32 + rh * 8];
#pragma unroll
      for (int n = 0; n < 2; ++n) {
        b1v[n] = *(const bf16x8*)&B1s[s][(wn * 32 + n * 16 + cl) * 64 + kk * 32 + rh * 8];
        b2v[n] = *(const bf16x8*)&B2s[s][(wn * 32 + n * 16 + cl) * 64 + kk * 32 + rh * 8];
      }
#pragma unroll
      for (int m = 0; m < 2; ++m)
#pragma unroll
        for (int n = 0; n < 2; ++n) {
          acc1[m][n] = MFMA16(af[m], b1v[n], acc1[m][n]);
          acc2[m][n] = MFMA16(af[m], b2v[n], acc2[m][n]);
        }
    }
    __builtin_amdgcn_sched_barrier(0);
    __builtin_amdgcn_s_barrier();
    __builtin_amdgcn_sched_barrier(0);
  }
#undef STSW

#pragma unroll
  for (int m = 0; m < 2; ++m)
#pragma unroll
    for (int n = 0; n < 2; ++n) {
      int row0 = brow + wm * 32 + m * 16 + rh * 4;
      int col  = bcol + wn * 32 + n * 16 + cl;
#pragma unroll
      for (int r = 0; r < 4; ++r) {
        float h1 = acc1[m][n][r], h2 = acc2[m][n][r];
        G[(size_t)(row0 + r) * 2048 + col] = (bf16)(h1 / (1.f + __expf(-h1)) * h2);
      }
    }
}

// ---------------- fused attention (r9 structure; PV on f32x2 slot-pairs) ----------------
__global__ __launch_bounds__(256, 2)
void fused_attn(const bf16* __restrict__ qm, const bf16* __restrict__ x,
                bf16* __restrict__ part, float* __restrict__ attn_sum)
{
  extern __shared__ __align__(16) char smem[];
  char* ss  = smem;                       // 32768
  char* ksl = smem + 32768;               // 2 * 16384
  float* p_lds = (float*)(smem + 65536);  // 128 * 20 f32

  const int lc = blockIdx.x, b = blockIdx.y;
  const int tid = threadIdx.x, wave = tid >> 6, lane = tid & 63;
  const int cl = lane & 15, rh = lane >> 4;

  const bf16* sb = qm + (size_t)b * 16 * 1024;
  {
    const int c16 = tid & 127, row2 = tid >> 7;
#pragma unroll
    for (int i = 0; i < 8; ++i) {
      int row = i * 2 + row2;
      int colb = (c16 * 16) ^ ((row & 7) << 4);
      gload16(sb + row * 1024 + colb / 2, ss + i * 4096 + wave * 1024);
    }
  }

  const bf16* kb = x + ((size_t)b * 2048 + lc * 128) * 1024;
  const int ksw  = ((lane & 7) ^ ((lane >> 3) & 7)) * 8;
  const int krow = wave * 8 + (lane >> 3);

#define STAGE_KS(KT) {                                                            \
    char* d_ = ksl + ((KT) & 1) * 16384;                                          \
    _Pragma("unroll")                                                             \
    for (int i = 0; i < 4; ++i)                                                   \
      gload16(kb + (size_t)(i * 32 + krow) * 1024 + (KT) * 64 + ksw,              \
              d_ + (i * 32 + wave * 8) * 128);                                    \
  }

  f32x4 acc[2] = {};
  STAGE_KS(0)
  for (int kt = 0; kt < 16; ++kt) {
    if (kt < 15) { STAGE_KS(kt + 1) }
    __builtin_amdgcn_sched_barrier(0);
    if (kt < 15) asm volatile("s_waitcnt vmcnt(4)" ::: "memory");
    else         asm volatile("s_waitcnt vmcnt(0)" ::: "memory");
    __builtin_amdgcn_sched_barrier(0);
    __builtin_amdgcn_s_barrier();
    const char* sbuf = ksl + (kt & 1) * 16384;
#pragma unroll
    for (int kk = 0; kk < 2; ++kk) {
      bf16x8 af = *(const bf16x8*)(ss + cl * 2048 +
                    ((kt * 128 + kk * 64 + rh * 16) ^ ((cl & 7) << 4)));
#pragma unroll
      for (int n = 0; n < 2; ++n) {
        int row = wave * 32 + n * 16 + cl;
        bf16x8 bfv = *(const bf16x8*)(sbuf + row * 128 +
                      ((kk * 64 + rh * 16) ^ ((row & 7) << 4)));
        acc[n] = MFMA16(af, bfv, acc[n]);
      }
    }
    __builtin_amdgcn_s_barrier();
    __builtin_amdgcn_sched_barrier(0);
  }
#undef STAGE_KS

  const float scale = 0.03125f;
  float rs[4] = {0.f, 0.f, 0.f, 0.f};
#pragma unroll
  for (int n = 0; n < 2; ++n) {
    float xv[4];
#pragma unroll
    for (int r = 0; r < 4; ++r) xv[r] = acc[n][r] * scale;
    float mx = fmaxf(fmaxf(xv[0], xv[1]), fmaxf(xv[2], xv[3]));
    mx = fmaxf(mx, __shfl_xor(mx, 16));
    mx = fmaxf(mx, __shfl_xor(mx, 32));
    float e[4], sm = 0.f;
#pragma unroll
    for (int r = 0; r < 4; ++r) { e[r] = __expf(xv[r] - mx); sm += e[r]; }
    sm += __shfl_xor(sm, 16);
    sm += __shfl_xor(sm, 32);
    float inv = 1.f / sm;
    f32x4 pk;
#pragma unroll
    for (int r = 0; r < 4; ++r) { float av = e[r] * inv; rs[r] += av; pk[r] = av; }
    int ll = wave * 32 + n * 16 + cl;
    *(f32x4*)&p_lds[ll * 20 + rh * 4] = pk;
  }
#pragma unroll
  for (int off = 1; off < 16; off <<= 1) {
#pragma unroll
    for (int r = 0; r < 4; ++r) rs[r] += __shfl_xor(rs[r], off);
  }
  if (cl == 0) {
#pragma unroll
    for (int r = 0; r < 4; ++r) atomicAdd(&attn_sum[b * 16 + rh * 4 + r], rs[r]);
  }
  __syncthreads();

  // ---- PV: f32x2 over slot pairs -> v_pk_fma_f32 (2 FMA/instr) ----
  const bf16* vb = x + ((size_t)b * 2048 + lc * 128) * 1024 + tid * 4;
  f32x2 pacc2[8][4] = {};
  for (int l = 0; l < 128; ++l) {
    bf16x4 vv = *(const bf16x4*)(vb + (size_t)l * 1024);
    f32x2 xs[4];
#pragma unroll
    for (int j = 0; j < 4; ++j) { float f = (float)vv[j]; xs[j][0] = f; xs[j][1] = f; }
    f32x2 p2[8];
#pragma unroll
    for (int sp = 0; sp < 8; ++sp) p2[sp] = *(const f32x2*)&p_lds[l * 20 + sp * 2];
#pragma unroll
    for (int sp = 0; sp < 8; ++sp)
#pragma unroll
      for (int j = 0; j < 4; ++j)
        pacc2[sp][j] += p2[sp] * xs[j];
  }
  bf16* pb = part + ((size_t)(lc * 32 + b) * 16) * 1024 + tid * 4;
#pragma unroll
  for (int n = 0; n < 16; ++n) {
    bf16x4 o;
#pragma unroll
    for (int r = 0; r < 4; ++r) o[r] = (bf16)pacc2[n >> 1][r][n & 1];
    *(bf16x4*)(pb + (size_t)n * 1024) = o;
  }
}

// sum 16 bf16 l-splits, normalize -> updraw bf16. grid 256 x 256thr, 8 elems/thread.
__global__ void updates_finalize(const bf16* __restrict__ part, const float* __restrict__ attn_sum,
                                 bf16* __restrict__ updraw)
{
  int idx8 = (blockIdx.x * 256 + threadIdx.x) * 8;   // over 512*1024
  int m = idx8 >> 10;
  float s[8] = {};
#pragma unroll
  for (int ls = 0; ls < 16; ++ls) {
    bf16x8 v = *(const bf16x8*)(part + idx8 + (size_t)ls * 524288);
#pragma unroll
    for (int j = 0; j < 8; ++j) s[j] += (float)v[j];
  }
  float inv = 1.f / (attn_sum[m] + 1e-8f);
  bf16x8 o;
#pragma unroll
  for (int j = 0; j < 8; ++j) o[j] = (bf16)(s[j] * inv);
  *(bf16x8*)(updraw + idx8) = o;
}

// ---------------- GRU pointwise + fused rmsnorm ----------------
__global__ __launch_bounds__(256)
void gru_pw_fused(const float* __restrict__ gi, const float* __restrict__ gh,
                  const float* __restrict__ bih, const float* __restrict__ bhh,
                  const float* __restrict__ g_sl,
                  float* __restrict__ slots, bf16* __restrict__ slots_bf,
                  bf16* __restrict__ s_bf, float* __restrict__ outp)
{
  const int m = blockIdx.x, tid = threadIdx.x;
  const int d0 = tid * 4;
  const size_t base = (size_t)m * 3072 + d0;
  f32x4 gir = *(const f32x4*)(gi + base),        ghr = *(const f32x4*)(gh + base);
  f32x4 giz = *(const f32x4*)(gi + base + 1024), ghz = *(const f32x4*)(gh + base + 1024);
  f32x4 gin = *(const f32x4*)(gi + base + 2048), ghn = *(const f32x4*)(gh + base + 2048);
  f32x4 br  = *(const f32x4*)(bih + d0),        bhr = *(const f32x4*)(bhh + d0);
  f32x4 bz  = *(const f32x4*)(bih + 1024 + d0), bhz = *(const f32x4*)(bhh + 1024 + d0);
  f32x4 bn  = *(const f32x4*)(bih + 2048 + d0), bhn = *(const f32x4*)(bhh + 2048 + d0);
  f32x4 h   = *(const f32x4*)(slots + (size_t)m * 1024 + d0);
  float o[4]; float ssum = 0.f;
#pragma unroll
  for (int j = 0; j < 4; ++j) {
    float r  = gir[j] + br[j] + ghr[j] + bhr[j];
    float z  = giz[j] + bz[j] + ghz[j] + bhz[j];
    float nn = gin[j] + bn[j];
    float hn = ghn[j] + bhn[j];
    r = 1.f / (1.f + expf(-r));
    z = 1.f / (1.f + expf(-z));
    nn = tanhf(nn + r * hn);
    o[j] = (1.f - z) * nn + z * h[j];
    ssum += o[j] * o[j];
  }
#pragma unroll
  for (int off = 32; off; off >>= 1) ssum += __shfl_xor(ssum, off);
  __shared__ float red[4];
  if ((tid & 63) == 0) red[tid >> 6] = ssum;
  __syncthreads();
  float tot = red[0] + red[1] + red[2] + red[3];
  float rsc = rsqrtf(tot * (1.f / 1024.f) + 1e-6f);
  f32x4 gv = *(const f32x4*)(g_sl + d0);
  f32x4 of; bf16x4 ob, sb;
#pragma unroll
  for (int j = 0; j < 4; ++j) { of[j] = o[j]; ob[j] = (bf16)o[j]; sb[j] = (bf16)(o[j] * rsc * gv[j]); }
  *(f32x4*)(slots + (size_t)m * 1024 + d0) = of;
  *(f32x4*)(outp  + (size_t)m * 1024 + d0) = of;
  *(bf16x4*)(slots_bf + (size_t)m * 1024 + d0) = ob;
  *(bf16x4*)(s_bf     + (size_t)m * 1024 + d0) = sb;
}

__global__ __launch_bounds__(256)
void init_slots_fused(const float* __restrict__ noise, const float* __restrict__ mu,
                      const float* __restrict__ sigma, const float* __restrict__ g_sl,
                      float* __restrict__ slots, bf16* __restrict__ slots_bf,
                      bf16* __restrict__ s_bf)
{
  const int m = blockIdx.x, tid = threadIdx.x;
  const int d0 = tid * 4;
  f32x4 nz = *(const f32x4*)(noise + (size_t)m * 1024 + d0);
  f32x4 mv = *(const f32x4*)(mu + d0);
  f32x4 sg = *(const f32x4*)(sigma + d0);
  float o[4]; float ssum = 0.f;
#pragma unroll
  for (int j = 0; j < 4; ++j) { o[j] = mv[j] + sg[j] * nz[j]; ssum += o[j] * o[j]; }
#pragma unroll
  for (int off = 32; off; off >>= 1) ssum += __shfl_xor(ssum, off);
  __shared__ float red[4];
  if ((tid & 63) == 0) red[tid >> 6] = ssum;
  __syncthreads();
  float tot = red[0] + red[1] + red[2] + red[3];
  float rsc = rsqrtf(tot * (1.f / 1024.f) + 1e-6f);
  f32x4 gv = *(const f32x4*)(g_sl + d0);
  f32x4 of; bf16x4 ob, sb;
#pragma unroll
  for (int j = 0; j < 4; ++j) { of[j] = o[j]; ob[j] = (bf16)o[j]; sb[j] = (bf16)(o[j] * rsc * gv[j]); }
  *(f32x4*)(slots + (size_t)m * 1024 + d0) = of;
  *(bf16x4*)(slots_bf + (size_t)m * 1024 + d0) = ob;
  *(bf16x4*)(s_bf     + (size_t)m * 1024 + d0) = sb;
}

__global__ __launch_bounds__(256)
void rmsnorm_cast(const float* __restrict__ x, const float* __restrict__ g, bf16* __restrict__ y)
{
  const int row = blockIdx.x, tid = threadIdx.x;
  float4 xv = ((const float4*)(x + (size_t)row * 1024))[tid];
  float ss = xv.x * xv.x + xv.y * xv.y + xv.z * xv.z + xv.w * xv.w;
#pragma unroll
  for (int off = 32; off; off >>= 1) ss += __shfl_xor(ss, off);
  __shared__ float red[4];
  if ((tid & 63) == 0) red[tid >> 6] = ss;
  __syncthreads();
  float tot = red[0] + red[1] + red[2] + red[3];
  float rs = rsqrtf(tot * (1.f / 1024.f) + 1e-6f);
  float4 gv = ((const float4*)g)[tid];
  bf16x4 o;
  o[0] = (bf16)(xv.x * rs * gv.x); o[1] = (bf16)(xv.y * rs * gv.y);
  o[2] = (bf16)(xv.z * rs * gv.z); o[3] = (bf16)(xv.w * rs * gv.w);
  *(bf16x4*)(y + (size_t)row * 1024 + tid * 4) = o;
}

// ---- batched transposes: z=0..2 Wq/Wk/Wv (1024^2); z=3 w3 [1024,2048] ----
__global__ __launch_bounds__(256)
void transpose_all(const float* __restrict__ Wq, const float* __restrict__ Wk,
                   const float* __restrict__ Wv, const float* __restrict__ w3,
                   bf16* __restrict__ wqT, bf16* __restrict__ wkT,
                   bf16* __restrict__ wvT, bf16* __restrict__ w3T)
{
  __shared__ float tile[32][33];
  const int z = blockIdx.z;
  const float* in; bf16* out; int R, C;
  if      (z == 0) { in = Wq; out = wqT; R = 1024; C = 1024; }
  else if (z == 1) { in = Wk; out = wkT; R = 1024; C = 1024; }
  else if (z == 2) { in = Wv; out = wvT; R = 1024; C = 1024; }
  else             { in = w3; out = w3T; R = 1024; C = 2048; }
  const int bx = blockIdx.x * 32, by = blockIdx.y * 32;
  if (bx >= C) return;
  const int tx = threadIdx.x & 31, ty = threadIdx.x >> 5;
#pragma unroll
  for (int i = 0; i < 32; i += 8)
    tile[ty + i][tx] = in[(size_t)(by + ty + i) * C + bx + tx];
  __syncthreads();
#pragma unroll
  for (int i = 0; i < 32; i += 8)
    out[(size_t)(bx + ty + i) * R + by + tx] = (bf16)tile[tx][ty + i];
}

// ---- flat cast: w1,w2 -> w12_bf ; Wih -> wih_bf ; Whh -> whh_b ----
__global__ void cast_all(const float* __restrict__ w1, const float* __restrict__ w2,
                         const float* __restrict__ Wih, const float* __restrict__ Whh,
                         bf16* __restrict__ w12_bf, bf16* __restrict__ wih_bf,
                         bf16* __restrict__ whh_b)
{
  int i = (blockIdx.x * 256 + threadIdx.x) * 4;      // over 10485760
  const float* src; bf16* dst; int o;
  if      (i < 2097152)  { src = w1;  dst = w12_bf; o = i; }
  else if (i < 4194304)  { src = w2;  dst = w12_bf + 2097152; o = i - 2097152; }
  else if (i < 7340032)  { src = Wih; dst = wih_bf; o = i - 4194304; }
  else                   { src = Whh; dst = whh_b;  o = i - 7340032; }
  float4 v = *(const float4*)(src + o);
  bf16x4 ov; ov[0] = (bf16)v.x; ov[1] = (bf16)v.y; ov[2] = (bf16)v.z; ov[3] = (bf16)v.w;
  *(bf16x4*)(dst + o) = ov;
}

// ---------------- host ----------------
extern "C" void kernel_launch(void* const* d_in, const int* in_sizes, int n_in,
                              void* d_out, int out_size, void* d_ws, size_t ws_size,
                              hipStream_t stream)
{
  const float* enc    = (const float*)d_in[0];
  const float* noise  = (const float*)d_in[1];
  const float* mu     = (const float*)d_in[2];
  const float* sigma  = (const float*)d_in[3];
  const float* g_in   = (const float*)d_in[4];
  const float* g_sl   = (const float*)d_in[5];
  const float* Wq     = (const float*)d_in[6];
  const float* Wk     = (const float*)d_in[7];
  const float* Wv     = (const float*)d_in[8];
  const float* w1     = (const float*)d_in[9];
  const float* w2     = (const float*)d_in[10];
  const float* w3     = (const float*)d_in[11];
  const float* Wih    = (const float*)d_in[12];
  const float* Whh    = (const float*)d_in[13];
  const float* bih    = (const float*)d_in[14];
  const float* bhh    = (const float*)d_in[15];

  char* p = (char*)d_ws;
  auto alloc = [&](size_t bytes) { char* r = p; p += (bytes + 255) & ~(size_t)255; return (void*)r; };

  bf16* inputs  = (bf16*)alloc((size_t)32 * 2048 * 1024 * 2);  // 128MB, K & V
  bf16* qm_w    = (bf16*)alloc((size_t)1024 * 1024 * 2);
  bf16* wqT_b   = (bf16*)alloc((size_t)1024 * 1024 * 2);
  bf16* wkT_b   = (bf16*)alloc((size_t)1024 * 1024 * 2);
  bf16* wvT_b   = (bf16*)alloc((size_t)1024 * 1024 * 2);
  bf16* w3T_b   = (bf16*)alloc((size_t)2048 * 1024 * 2);
  bf16* w12_bf  = (bf16*)alloc((size_t)4096 * 1024 * 2);
  bf16* w12v    = (bf16*)alloc((size_t)4096 * 1024 * 2);
  bf16* wih_bf  = (bf16*)alloc((size_t)3072 * 1024 * 2);
  bf16* wih3_b  = (bf16*)alloc((size_t)3072 * 2048 * 2);
  bf16* whh_b   = (bf16*)alloc((size_t)3072 * 1024 * 2);
  float* slots  = (float*)alloc(512 * 1024 * 4);
  bf16* slots_bf= (bf16*)alloc(512 * 1024 * 2);
  bf16* s_bf    = (bf16*)alloc(512 * 1024 * 2);
  bf16* qm_bf   = (bf16*)alloc(512 * 1024 * 2);
  float* attn_sum = (float*)alloc(32 * 16 * 4);
  bf16* part    = (bf16*)alloc((size_t)16 * 512 * 1024 * 2);   // 16MB bf16
  bf16* updraw  = (bf16*)alloc(512 * 1024 * 2);
  bf16* g_bf    = (bf16*)alloc((size_t)512 * 2048 * 2);
  float* gif    = (float*)alloc((size_t)512 * 3072 * 4);
  float* ghf    = (float*)alloc((size_t)512 * 3072 * 4);

  // ---- precompute: 3 launches ----
  transpose_all<<<dim3(64, 32, 4), 256, 0, stream>>>(Wq, Wk, Wv, w3, wqT_b, wkT_b, wvT_b, w3T_b);
  cast_all<<<10240, 256, 0, stream>>>(w1, w2, Wih, Whh, w12_bf, wih_bf, whh_b);
  gemm_pre128<<<704, 256, 0, stream>>>(wkT_b, wqT_b, qm_w, w12_bf, wvT_b, w12v, wih_bf, w3T_b, wih3_b);

  // ---- stage 1 ----
  rmsnorm_cast<<<65536, 256, 0, stream>>>(enc, g_in, inputs);
  init_slots_fused<<<512, 256, 0, stream>>>(noise, mu, sigma, g_sl, slots, slots_bf, s_bf);

  hipFuncSetAttribute(reinterpret_cast<const void*>(fused_attn),
                      hipFuncAttributeMaxDynamicSharedMemorySize, 75776);

  // ---- iterations (6 launches each) ----
  for (int it = 0; it < 4; ++it) {
    gemm_bt64<0><<<dim3(16, 8, 1), 256, 0, stream>>>(s_bf, qm_w, qm_bf, s_bf, qm_w, qm_bf,
                                                     1024, 1024, 1024, attn_sum);
    fused_attn<<<dim3(16, 32), 256, 75776, stream>>>(qm_bf, inputs, part, attn_sum);
    updates_finalize<<<256, 256, 0, stream>>>(part, attn_sum, updraw);
    gemm_swiglu<<<dim3(32, 8), 256, 0, stream>>>(updraw, w12v, g_bf);
    gemm_bt64<1><<<dim3(48, 8, 2), 256, 0, stream>>>(g_bf, wih3_b, gif, slots_bf, whh_b, ghf,
                                                     3072, 2048, 1024, nullptr);
    float* outp = (it == 3) ? (float*)d_out : slots;
    gru_pw_fused<<<512, 256, 0, stream>>>(gif, ghf, bih, bhh, g_sl, slots, slots_bf, s_bf, outp);
  }
}